// Round 7
// baseline (2464.140 us; speedup 1.0000x reference)
//
#include <hip/hip_runtime.h>
#include <cstdint>
#include <cstddef>

#define BATCH 64
#define SEQ   128
#define EMB   512
#define HID   1024
#define NCLS  10000
#define NG    4096      // 4*HID gate columns
#define NOP   10048     // padded output columns (314 * 32)
#define BH    (BATCH * HID)   // one h slot (elements)

typedef __attribute__((ext_vector_type(8))) short short8;
typedef __attribute__((ext_vector_type(4))) short short4v;
typedef __attribute__((ext_vector_type(4))) float floatx4;
typedef unsigned short u16;
typedef unsigned char  u8;
typedef unsigned long long u64;

// dynamic LDS: DOUBLE-BUFFERED red[2][8][64][36] fp32 (W lives in registers)
#define RED_PAD    36
#define RED_SIZE   (8 * 64 * RED_PAD)        // floats per buffer
#define LDS_BYTES  (2 * RED_SIZE * 4)        // 147456

__device__ __forceinline__ u16 f2bf(float x) {
    union { float f; unsigned u; } v; v.f = x;
    unsigned r = v.u + 0x7fffu + ((v.u >> 16) & 1u);   // RNE
    return (u16)(r >> 16);
}
__device__ __forceinline__ float sigm(float x) { return 1.f / (1.f + __expf(-x)); }
__device__ __forceinline__ unsigned umin2(unsigned a, unsigned b) { return a < b ? a : b; }

// all 8 bytes of v >= tgt  (per-wave stamp bytes of one producer block)
__device__ __forceinline__ bool ok8(u64 v, unsigned tgt) {
    unsigned a = (unsigned)v, b = (unsigned)(v >> 32);
    unsigned m = umin2(umin2(a & 255u, (a >> 8) & 255u),
                       umin2((a >> 16) & 255u, a >> 24));
    unsigned n = umin2(umin2(b & 255u, (b >> 8) & 255u),
                       umin2((b >> 16) & 255u, b >> 24));
    return umin2(m, n) >= tgt;
}

// Per-WAVE subset wait on u64-per-block stamps: lanes ln < n poll block
// (lo+ln); wave spins until every polled block's 8 wave-bytes >= tgt.
// Agent-scope (sc1) loads bypass L2 -> always see fresh L3.
__device__ __forceinline__ void wave_wait_blocks(const u64* flags, int lo,
                                                 int n, unsigned tgt) {
    const int ln = threadIdx.x & 63;
    const u64* p = flags + lo + ln;
    for (;;) {
        bool ok = true;
        if (ln < n)
            ok = ok8(__hip_atomic_load(p, __ATOMIC_RELAXED, __HIP_MEMORY_SCOPE_AGENT), tgt);
        if (__all(ok)) break;
        __builtin_amdgcn_s_sleep(1);
    }
}

// ---------------------------------------------------------------------------
// Pack 4 gate matrices [K][1024] fp32 -> Wcat k-inner-8 bf16 layout:
//   element (k, col n) at dst[((k>>3)*NG + n)*8 + (k&7)],  n = unit*4 + gate.
// ---------------------------------------------------------------------------
__global__ void pack_gates(const float* __restrict__ s0, const float* __restrict__ s1,
                           const float* __restrict__ s2, const float* __restrict__ s3,
                           u16* __restrict__ dst, int kgroups, int kg_off) {
    int t = blockIdx.x * blockDim.x + threadIdx.x;
    if (t >= kgroups * HID) return;
    int u  = t & (HID - 1);
    int kg = t >> 10;
    u16* out = dst + ((size_t)(kg + kg_off) * NG + (size_t)u * 4) * 8;
#pragma unroll
    for (int g = 0; g < 4; ++g) {
        const float* s = (g == 0) ? s0 : (g == 1) ? s1 : (g == 2) ? s2 : s3;
        short8 v;
#pragma unroll
        for (int j = 0; j < 8; ++j)
            v[j] = (short)f2bf(s[(size_t)(kg * 8 + j) * HID + u]);
        *(short8*)(out + g * 8) = v;
    }
}

// W_out [1024][10000] fp32 -> padded k-inner-8 bf16 [(128)][10048][8]
__global__ void pack_wout(const float* __restrict__ src, u16* __restrict__ dst) {
    int t = blockIdx.x * blockDim.x + threadIdx.x;
    if (t >= 128 * NCLS) return;
    int n  = t % NCLS;
    int kg = t / NCLS;
    short8 v;
#pragma unroll
    for (int j = 0; j < 8; ++j)
        v[j] = (short)f2bf(src[(size_t)(kg * 8 + j) * NCLS + n]);
    *(short8*)(dst + ((size_t)kg * NOP + n) * 8) = v;
}

// Embedding, block-major-k layout: E[s][kg][m][j] = bf16(C[X[m][s]][kg*8+j])
__global__ void embed_k(const int* __restrict__ X, const float* __restrict__ C,
                        u16* __restrict__ E) {
    const int sb = blockIdx.x;             // s*64 + m
    const int s = sb >> 6, m = sb & 63;
    const int row = X[m * SEQ + s];
    const floatx4* src = (const floatx4*)(C + (size_t)row * EMB);
    const int t = threadIdx.x;             // 128 threads, 4 elems each
    floatx4 v = src[t];
    short4v o;
    o[0] = (short)f2bf(v[0]); o[1] = (short)f2bf(v[1]);
    o[2] = (short)f2bf(v[2]); o[3] = (short)f2bf(v[3]);
    u16* dst = E + (size_t)s * (64 * 512) + (size_t)(t >> 1) * 512 + m * 8 + (t & 1) * 4;
    *(short4v*)dst = o;
}

// ---------------------------------------------------------------------------
// One LSTM step with weight-stationary registers. 8 waves = 8-way k-split.
// h slots BLOCK-MAJOR: h[kg][m][j]. Caller issued ALL areg loads + pinned
// with sched_barrier. ONE barrier per tick (lgkm-only, double-buffered red).
// Tail: reduce, epilogue, sc1 h-stores, per-wave vmcnt(0) drain, per-wave
// stamp byte (lane 0) -- no block-wide end-of-tick barrier.
// ---------------------------------------------------------------------------
template<int NS, bool WRITE_H>
__device__ __forceinline__ void compute_tick(
    float* __restrict__ redb,                 // selected buffer [8][64][RED_PAD]
    const short8 (&wreg)[NS][2],
    const short8 (&areg)[NS][4],
    u16* __restrict__ ho, u16* __restrict__ Hout,
    u8* __restrict__ stamp, unsigned sval,
    float& c, float bF, float bI, float bC, float bO, int ub)
{
    const int tid = threadIdx.x;
    const int kw = tid >> 6, l = tid & 63;
    const int ml = l & 15, q = l >> 4;

    floatx4 acc[4][2];
#pragma unroll
    for (int mt = 0; mt < 4; ++mt)
#pragma unroll
        for (int ch = 0; ch < 2; ++ch)
            acc[mt][ch] = (floatx4){0.f, 0.f, 0.f, 0.f};

#pragma unroll
    for (int ci = 0; ci < NS; ++ci)
#pragma unroll
        for (int mt = 0; mt < 4; ++mt) {
            acc[mt][0] = __builtin_amdgcn_mfma_f32_16x16x32_bf16(
                areg[ci][mt], wreg[ci][0], acc[mt][0], 0, 0, 0);
            acc[mt][1] = __builtin_amdgcn_mfma_f32_16x16x32_bf16(
                areg[ci][mt], wreg[ci][1], acc[mt][1], 0, 0, 0);
        }

    // partial -> red[kw][row][col]; D mapping: row = mt*16+q*4+r, col = ch*16+ml
#pragma unroll
    for (int mt = 0; mt < 4; ++mt)
#pragma unroll
        for (int ch = 0; ch < 2; ++ch)
#pragma unroll
            for (int r = 0; r < 4; ++r)
                redb[((size_t)kw * 64 + mt * 16 + q * 4 + r) * RED_PAD + ch * 16 + ml]
                    = acc[mt][ch][r];

    // single per-tick barrier: LDS-only (h stores of prev tick already drained
    // per-wave; no vmcnt drain here -> round-1 lesson)
    asm volatile("s_waitcnt lgkmcnt(0)" ::: "memory");
    __builtin_amdgcn_s_barrier();
    __builtin_amdgcn_sched_barrier(0);

    // block reduction over 8 k-slices + epilogue (order identical to round 6)
    const int m = tid >> 3, u = tid & 7;
    const int nl = u * 4;
    float p0 = 0.f, p1 = 0.f, p2 = 0.f, p3 = 0.f;
#pragma unroll
    for (int k2 = 0; k2 < 8; ++k2) {
        floatx4 rv = *(const floatx4*)&redb[((size_t)k2 * 64 + m) * RED_PAD + nl];
        p0 += rv[0]; p1 += rv[1]; p2 += rv[2]; p3 += rv[3];
    }
    float f = sigm(p0 + bF);
    float i = sigm(p1 + bI);
    float g = tanhf(p2 + bC);
    float o = sigm(p3 + bO);
    float cc = f * c + i * g;
    c = cc;
    u16 hb = f2bf(o * tanhf(cc));
    // block-major: offset ub*512 + m*8 + u == ub*512 + tid (contiguous 1KB)
    __hip_atomic_store(&ho[(size_t)ub * 512 + tid], hb,
                       __ATOMIC_RELAXED, __HIP_MEMORY_SCOPE_AGENT);
    if (WRITE_H)
        __hip_atomic_store(&Hout[(size_t)ub * 512 + tid], hb,
                           __ATOMIC_RELAXED, __HIP_MEMORY_SCOPE_AGENT);

    // per-wave drain + stamp (this wave's stores are at L3; lane 0 signals)
    asm volatile("s_waitcnt vmcnt(0)" ::: "memory");
    if (l == 0)
        __hip_atomic_store(stamp + kw, (u8)sval,
                           __ATOMIC_RELAXED, __HIP_MEMORY_SCOPE_AGENT);
}

// ---------------------------------------------------------------------------
// Persistent kernel. 256 blocks x 512 thr, 147456 B LDS, 1 block/CU.
// Coherence (validated rounds 0-6): NO fences in tick loop; fresh per-tick
// chain addresses; sc1 write-through producers; block-major h/E layout.
// THIS ROUND:
//   - amdgpu_waves_per_eu(2,2): pins compiler occupancy target to the
//     LDS-enforced 2 waves/SIMD -> VGPR cap 256 (round-6's 128-cap was the
//     compiler guessing 4 waves/SIMD under dynamic LDS) -> all 32 fragment
//     loads stay in flight.
//   - ONE barrier per tick: red[] double-buffered (buf = t&1); end-of-tick
//     __syncthreads + tid0 stamp replaced by per-wave vmcnt(0)+stamp byte.
//   - flags = u64 per producer block (8 wave-bytes); consumers poll min-byte.
// ---------------------------------------------------------------------------
struct PArgs {
    const u16 *E, *Wcat0, *Wcat1;
    u16 *H, *h0c, *h1c;     // h chains: 129 slots of BH, block-major layout
    const float *b_f, *b_i, *b_C, *b_o, *b_f1, *b_i1, *b_C1, *b_o1;
    unsigned* sync;          // flags0 u64[128] @ +0, flags1 u64[128] @ +4096
};

__global__ void __launch_bounds__(512, 2)
__attribute__((amdgpu_waves_per_eu(2, 2)))
persist_k(PArgs a) {
    extern __shared__ float redf[];        // [2][8][64][RED_PAD]

    const int b   = blockIdx.x;
    const int ub  = b & 127;
    const int tid = threadIdx.x;
    const bool L0 = (b < 128);

    const int kw = tid >> 6, l = tid & 63;
    const int ml = l & 15, q = l >> 4;

    // per-thread epilogue state (mapping fixed across ticks)
    const int ug = ub * 8 + (tid & 7);
    const float bF = L0 ? a.b_f[ug] : a.b_f1[ug];
    const float bI = L0 ? a.b_i[ug] : a.b_i1[ug];
    const float bC = L0 ? a.b_C[ug] : a.b_C1[ug];
    const float bO = L0 ? a.b_o[ug] : a.b_o1[ug];
    float c = 0.f;

    const u64* flags0 = (const u64*)a.sync;                 // u64[128]
    const u64* flags1 = (const u64*)((u8*)a.sync + 4096);   // u64[128]
    u8* my0 = (u8*)a.sync + (size_t)ub * 8;
    u8* my1 = (u8*)a.sync + 4096 + (size_t)ub * 8;

    if (L0) {
        // wave kw owns k-steps S = kw*6 .. kw*6+5 (S<16: E, S>=16: h0)
        short8 wreg[6][2];
#pragma unroll
        for (int ci = 0; ci < 6; ++ci)
#pragma unroll
            for (int ch = 0; ch < 2; ++ch) {
                const int kg = (kw * 6 + ci) * 4 + q;
                wreg[ci][ch] = *(const short8*)(
                    a.Wcat0 + ((size_t)kg * NG + ub * 32 + ch * 16 + ml) * 8);
            }
        // h source blocks for this wave: kg = (S-16)*4 + q, q = 0..3
        const int Smax = kw * 6 + 5;
        const int Smin = (kw * 6 > 16) ? kw * 6 : 16;
        const bool hasH = (Smax >= 16);
        const int blo  = hasH ? (Smin - 16) * 4 : 0;
        const int bn   = hasH ? (Smax - Smin + 1) * 4 : 0;

        for (int t = 0; t < 128; ++t) {
            short8 areg[6][4];
            const u16* Et  = a.E   + (size_t)t * (64 * 512);
            const u16* hin = a.h0c + (size_t)t * BH;
            // E-part loads (gate-free; issued before the poll)
#pragma unroll
            for (int ci = 0; ci < 6; ++ci) {
                const int S = kw * 6 + ci;             // wave-uniform
                if (S < 16) {
                    const int kg = S * 4 + q;
#pragma unroll
                    for (int mt = 0; mt < 4; ++mt)
                        areg[ci][mt] = *(const short8*)(
                            Et + (size_t)kg * 512 + (mt * 16 + ml) * 8);
                }
            }
            asm volatile("" ::: "memory");
            if (hasH && t > 0) wave_wait_blocks(flags0, blo, bn, (unsigned)t);
            asm volatile("" ::: "memory");
            // h-part loads (h0c[t] complete per this wave's subset stamps)
#pragma unroll
            for (int ci = 0; ci < 6; ++ci) {
                const int S = kw * 6 + ci;
                if (S >= 16) {
                    const int kg = (S - 16) * 4 + q;
#pragma unroll
                    for (int mt = 0; mt < 4; ++mt)
                        areg[ci][mt] = *(const short8*)(
                            hin + (size_t)kg * 512 + (mt * 16 + ml) * 8);
                }
            }
            // pin: loads above, MFMAs below (counted vmcnt over full pipeline)
            __builtin_amdgcn_sched_barrier(0);
            compute_tick<6, true>(redf + (size_t)(t & 1) * RED_SIZE, wreg, areg,
                                  a.h0c + (size_t)(t + 1) * BH,
                                  a.H + (size_t)t * BH,
                                  my0, (unsigned)(t + 1),
                                  c, bF, bI, bC, bO, ub);
        }
    } else {
        // wave kw owns k-steps S = kw*8 .. kw*8+7; kw<4 -> H, kw>=4 -> h1c
        short8 wreg[8][2];
#pragma unroll
        for (int ci = 0; ci < 8; ++ci)
#pragma unroll
            for (int ch = 0; ch < 2; ++ch) {
                const int kg = (kw * 8 + ci) * 4 + q;
                wreg[ci][ch] = *(const short8*)(
                    a.Wcat1 + ((size_t)kg * NG + ub * 32 + ch * 16 + ml) * 8);
            }
        const int kg0 = (kw & 3) * 8;      // k-group base within source
        const int blo = kg0 * 4;           // 32 producer blocks for this wave

        for (int s = 0; s < 128; ++s) {
            short8 areg[8][4];
            const u16* src;
            if (kw >= 4) {
                if (s > 0) wave_wait_blocks(flags1, blo, 32, (unsigned)s);
                src = a.h1c + (size_t)s * BH;
            } else {
                wave_wait_blocks(flags0, blo, 32, (unsigned)(s + 1));
                src = a.H + (size_t)s * BH;
            }
            asm volatile("" ::: "memory");
            // issue ALL 32 fragment loads back-to-back (deep MLP)
#pragma unroll
            for (int ci = 0; ci < 8; ++ci) {
                const int kg = (kg0 + ci) * 4 + q;
#pragma unroll
                for (int mt = 0; mt < 4; ++mt)
                    areg[ci][mt] = *(const short8*)(
                        src + (size_t)kg * 512 + (mt * 16 + ml) * 8);
            }
            // pin: loads above, MFMAs below (counted vmcnt over full pipeline)
            __builtin_amdgcn_sched_barrier(0);
            compute_tick<8, false>(redf + (size_t)(s & 1) * RED_SIZE, wreg, areg,
                                   a.h1c + (size_t)(s + 1) * BH, nullptr,
                                   my1, (unsigned)(s + 1),
                                   c, bF, bI, bC, bO, ub);
        }
    }
    // final h1 = h1c + 128*BH (block-major); out_gemm reads that layout
}

// out[64][10000] = h1 @ W_out + b_out   (314 blocks x 32 cols)
// h1 is block-major: element (row m, col k) at h1[(k>>3)*512 + m*8 + (k&7)]
__global__ void __launch_bounds__(256) out_gemm(
    const u16* __restrict__ h1, const u16* __restrict__ W,
    const float* __restrict__ bout, float* __restrict__ out)
{
    __shared__ float red[4][64][33];
    const int tid = threadIdx.x;
    const int w = tid >> 6, l = tid & 63;
    const int ml = l & 15, q = l >> 4;
    const int n0 = blockIdx.x * 32;

    floatx4 acc[4][2];
#pragma unroll
    for (int mi = 0; mi < 4; ++mi)
#pragma unroll
        for (int ni = 0; ni < 2; ++ni)
            acc[mi][ni] = (floatx4){0.f, 0.f, 0.f, 0.f};

#pragma unroll
    for (int ci = 0; ci < 8; ++ci) {
        const int k = (ci * 4 + w) << 5;
        const int kg = (k >> 3) + q;               // k-group of this fragment
        const u16* ar = h1 + (size_t)kg * 512 + ml * 8;
        short8 a0 = *(const short8*)(ar);
        short8 a1 = *(const short8*)(ar + 16 * 8);
        short8 a2 = *(const short8*)(ar + 32 * 8);
        short8 a3 = *(const short8*)(ar + 48 * 8);
        const u16* br = W + ((size_t)((k >> 3) + q) * NOP + n0 + ml) * 8;
        short8 b0 = *(const short8*)(br);
        short8 b1 = *(const short8*)(br + 16 * 8);
        acc[0][0] = __builtin_amdgcn_mfma_f32_16x16x32_bf16(a0, b0, acc[0][0], 0, 0, 0);
        acc[1][0] = __builtin_amdgcn_mfma_f32_16x16x32_bf16(a1, b0, acc[1][0], 0, 0, 0);
        acc[2][0] = __builtin_amdgcn_mfma_f32_16x16x32_bf16(a2, b0, acc[2][0], 0, 0, 0);
        acc[3][0] = __builtin_amdgcn_mfma_f32_16x16x32_bf16(a3, b0, acc[3][0], 0, 0, 0);
        acc[0][1] = __builtin_amdgcn_mfma_f32_16x16x32_bf16(a0, b1, acc[0][1], 0, 0, 0);
        acc[1][1] = __builtin_amdgcn_mfma_f32_16x16x32_bf16(a1, b1, acc[1][1], 0, 0, 0);
        acc[2][1] = __builtin_amdgcn_mfma_f32_16x16x32_bf16(a2, b1, acc[2][1], 0, 0, 0);
        acc[3][1] = __builtin_amdgcn_mfma_f32_16x16x32_bf16(a3, b1, acc[3][1], 0, 0, 0);
    }

#pragma unroll
    for (int mi = 0; mi < 4; ++mi)
#pragma unroll
        for (int ni = 0; ni < 2; ++ni)
#pragma unroll
            for (int r = 0; r < 4; ++r)
                red[w][mi * 16 + q * 4 + r][ni * 16 + ml] = acc[mi][ni][r];
    __syncthreads();

    const int m = tid >> 2;
#pragma unroll
    for (int jj = 0; jj < 8; ++jj) {
        const int nl = (tid & 3) * 8 + jj;
        const int n = n0 + nl;
        if (n < NCLS) {
            float v = red[0][m][nl] + red[1][m][nl] + red[2][m][nl] + red[3][m][nl] + bout[n];
            out[(size_t)m * NCLS + n] = v;
        }
    }
}

// ---------------------------------------------------------------------------
extern "C" void kernel_launch(void* const* d_in, const int* in_sizes, int n_in,
                              void* d_out, int out_size, void* d_ws, size_t ws_size,
                              hipStream_t stream) {
    (void)in_sizes; (void)n_in; (void)out_size; (void)ws_size;
    const int*   X     = (const int*)  d_in[0];
    const float* C     = (const float*)d_in[1];
    const float* W_fx  = (const float*)d_in[2];
    const float* W_fh  = (const float*)d_in[3];
    const float* W_ix  = (const float*)d_in[4];
    const float* W_ih  = (const float*)d_in[5];
    const float* W_Cx  = (const float*)d_in[6];
    const float* W_Ch  = (const float*)d_in[7];
    const float* W_ox  = (const float*)d_in[8];
    const float* W_oh  = (const float*)d_in[9];
    const float* W_fx1 = (const float*)d_in[10];
    const float* W_fh1 = (const float*)d_in[11];
    const float* W_ix1 = (const float*)d_in[12];
    // d_in[13] = W_ih1 — unused: reference reuses W_ih in layer-1 i-gate (bug kept)
    const float* W_Cx1 = (const float*)d_in[14];
    const float* W_Ch1 = (const float*)d_in[15];
    const float* W_ox1 = (const float*)d_in[16];
    const float* W_oh1 = (const float*)d_in[17];
    const float* W_out = (const float*)d_in[18];
    const float* b_f   = (const float*)d_in[19];
    const float* b_i   = (const float*)d_in[20];
    const float* b_C   = (const float*)d_in[21];
    const float* b_o   = (const float*)d_in[22];
    const float* b_f1  = (const float*)d_in[23];
    const float* b_i1  = (const float*)d_in[24];
    const float* b_C1  = (const float*)d_in[25];
    const float* b_o1  = (const float*)d_in[26];
    const float* b_out = (const float*)d_in[27];
    float* out = (float*)d_out;

    // workspace carve (~105 MB)
    uint8_t* ws = (uint8_t*)d_ws;
    const size_t SZ_WCAT0 = (size_t)1536 * NG * 2;      // 12 MB
    const size_t SZ_WCAT1 = (size_t)2048 * NG * 2;      // 16 MB
    const size_t SZ_WOUTP = (size_t)1024 * NOP * 2;     // ~20 MB
    const size_t SZ_E     = (size_t)SEQ * BATCH * EMB * 2;    // 8 MB
    const size_t SZ_H     = (size_t)SEQ * BH * 2;             // 16 MB
    const size_t SZ_HC    = (size_t)(SEQ + 1) * BH * 2;       // 16.6 MB per chain
    u16*   Wcat0 = (u16*)ws;                         ws += SZ_WCAT0;
    u16*   Wcat1 = (u16*)ws;                         ws += SZ_WCAT1;
    u16*   WoutP = (u16*)ws;                         ws += SZ_WOUTP;
    u16*   E     = (u16*)ws;                         ws += SZ_E;
    u16*   H     = (u16*)ws;                         ws += SZ_H;
    u16*   h0c   = (u16*)ws;                         ws += SZ_HC;
    u16*   h1c   = (u16*)ws;                         ws += SZ_HC;
    unsigned* syncw = (unsigned*)ws;                 ws += 8192;

    // allow 147456 B dynamic LDS (host-side, capture-safe; <=147968 validated)
    hipFuncSetAttribute((const void*)persist_k,
                        hipFuncAttributeMaxDynamicSharedMemorySize, LDS_BYTES);

    // --- pack weights + embed (parallel prep work)
    pack_gates<<<256, 256, 0, stream>>>(W_fx, W_ix, W_Cx, W_ox, Wcat0, 64, 0);
    pack_gates<<<512, 256, 0, stream>>>(W_fh, W_ih, W_Ch, W_oh, Wcat0, 128, 64);
    pack_gates<<<512, 256, 0, stream>>>(W_fx1, W_ix1, W_Cx1, W_ox1, Wcat1, 128, 0);
    pack_gates<<<512, 256, 0, stream>>>(W_fh1, W_ih, W_Ch1, W_oh1, Wcat1, 128, 128);
    hipMemsetAsync(WoutP, 0, SZ_WOUTP, stream);
    pack_wout<<<(128 * NCLS + 255) / 256, 256, 0, stream>>>(W_out, WoutP);
    embed_k<<<SEQ * BATCH, 128, 0, stream>>>(X, C, E);

    // --- zero slot 0 of both h chains + sync flags
    hipMemsetAsync(h0c, 0, (size_t)BH * 2, stream);
    hipMemsetAsync(h1c, 0, (size_t)BH * 2, stream);
    hipMemsetAsync(syncw, 0, 8192, stream);

    // --- the whole recurrence in one launch
    PArgs pa;
    pa.E = E; pa.Wcat0 = Wcat0; pa.Wcat1 = Wcat1;
    pa.H = H; pa.h0c = h0c; pa.h1c = h1c;
    pa.b_f = b_f; pa.b_i = b_i; pa.b_C = b_C; pa.b_o = b_o;
    pa.b_f1 = b_f1; pa.b_i1 = b_i1; pa.b_C1 = b_C1; pa.b_o1 = b_o1;
    pa.sync = syncw;
    persist_k<<<256, 512, LDS_BYTES, stream>>>(pa);

    // --- output projection (kernel boundary = full coherence for h1c final slot)
    out_gemm<<<314, 256, 0, stream>>>(h1c + (size_t)SEQ * BH, WoutP, b_out, out);
}

// Round 8
// 887.992 us; speedup vs baseline: 2.7750x; 2.7750x over previous
//
#include <hip/hip_runtime.h>
#include <cstdint>
#include <cstddef>

#define BATCH 64
#define SEQ   128
#define EMB   512
#define HID   1024
#define NCLS  10000
#define NG    4096      // 4*HID gate columns
#define NOP   10048     // padded output columns (314 * 32)
#define BH    (BATCH * HID)   // one h slot (elements)

typedef __attribute__((ext_vector_type(8))) short short8;
typedef __attribute__((ext_vector_type(4))) short short4v;
typedef __attribute__((ext_vector_type(4))) float floatx4;
typedef unsigned short u16;
typedef unsigned char  u8;
typedef unsigned long long u64;

// dynamic LDS: red[8][64][36] fp32 only (W lives in registers) -- round 6
#define RED_PAD    36
#define LDS_BYTES  (8 * 64 * RED_PAD * 4)   // 73728

__device__ __forceinline__ u16 f2bf(float x) {
    union { float f; unsigned u; } v; v.f = x;
    unsigned r = v.u + 0x7fffu + ((v.u >> 16) & 1u);   // RNE
    return (u16)(r >> 16);
}
__device__ __forceinline__ float sigm(float x) { return 1.f / (1.f + __expf(-x)); }

// Forced-MLP 16B load: volatile asm with distinct "=v" outputs keeps every
// destination live -> RA cannot serialize the load stream into reuse groups.
// ap = 64-bit byte address (VGPR pair); imm covers the ci-pair x mt fan-out.
#define GLD(dst, ap, IMM) \
    asm volatile("global_load_dwordx4 %0, %1, off offset:" #IMM \
                 : "=v"(dst) : "v"(ap))
// pair covering ci at ap-4096 (A0) and ap+0 (A1); mt stride 256B
#define LOADPAIR(A0, A1, ap) \
    GLD(A0[0], ap, -4096); GLD(A0[1], ap, -3840); \
    GLD(A0[2], ap, -3584); GLD(A0[3], ap, -3328); \
    GLD(A1[0], ap,     0); GLD(A1[1], ap,   256); \
    GLD(A1[2], ap,   512); GLD(A1[3], ap,   768)

// Per-WAVE subset wait: lanes ln < n poll line (lo+ln) (64B, 4 packed byte
// stamps in its first u32); wave spins until all polled stamps >= tgt.
// Agent-scope (sc1) loads bypass L2 -> always see fresh L3.  [round 6]
__device__ __forceinline__ void wave_wait_range(const unsigned* lines, int lo,
                                                int n, unsigned tgt) {
    const int ln = threadIdx.x & 63;
    const unsigned* p = lines + (size_t)(lo + ln) * 16;
    for (;;) {
        bool ok = true;
        if (ln < n) {
            unsigned v = __hip_atomic_load(p, __ATOMIC_RELAXED, __HIP_MEMORY_SCOPE_AGENT);
            ok = ((v & 255u) >= tgt) && (((v >> 8) & 255u) >= tgt) &&
                 (((v >> 16) & 255u) >= tgt) && ((v >> 24) >= tgt);
        }
        if (__all(ok)) break;
        __builtin_amdgcn_s_sleep(1);
    }
}

// ---------------------------------------------------------------------------
// Pack 4 gate matrices [K][1024] fp32 -> Wcat k-inner-8 bf16 layout:
//   element (k, col n) at dst[((k>>3)*NG + n)*8 + (k&7)],  n = unit*4 + gate.
// ---------------------------------------------------------------------------
__global__ void pack_gates(const float* __restrict__ s0, const float* __restrict__ s1,
                           const float* __restrict__ s2, const float* __restrict__ s3,
                           u16* __restrict__ dst, int kgroups, int kg_off) {
    int t = blockIdx.x * blockDim.x + threadIdx.x;
    if (t >= kgroups * HID) return;
    int u  = t & (HID - 1);
    int kg = t >> 10;
    u16* out = dst + ((size_t)(kg + kg_off) * NG + (size_t)u * 4) * 8;
#pragma unroll
    for (int g = 0; g < 4; ++g) {
        const float* s = (g == 0) ? s0 : (g == 1) ? s1 : (g == 2) ? s2 : s3;
        short8 v;
#pragma unroll
        for (int j = 0; j < 8; ++j)
            v[j] = (short)f2bf(s[(size_t)(kg * 8 + j) * HID + u]);
        *(short8*)(out + g * 8) = v;
    }
}

// W_out [1024][10000] fp32 -> padded k-inner-8 bf16 [(128)][10048][8]
__global__ void pack_wout(const float* __restrict__ src, u16* __restrict__ dst) {
    int t = blockIdx.x * blockDim.x + threadIdx.x;
    if (t >= 128 * NCLS) return;
    int n  = t % NCLS;
    int kg = t / NCLS;
    short8 v;
#pragma unroll
    for (int j = 0; j < 8; ++j)
        v[j] = (short)f2bf(src[(size_t)(kg * 8 + j) * NCLS + n]);
    *(short8*)(dst + ((size_t)kg * NOP + n) * 8) = v;
}

// Embedding, block-major-k layout: E[s][kg][m][j] = bf16(C[X[m][s]][kg*8+j])
__global__ void embed_k(const int* __restrict__ X, const float* __restrict__ C,
                        u16* __restrict__ E) {
    const int sb = blockIdx.x;             // s*64 + m
    const int s = sb >> 6, m = sb & 63;
    const int row = X[m * SEQ + s];
    const floatx4* src = (const floatx4*)(C + (size_t)row * EMB);
    const int t = threadIdx.x;             // 128 threads, 4 elems each
    floatx4 v = src[t];
    short4v o;
    o[0] = (short)f2bf(v[0]); o[1] = (short)f2bf(v[1]);
    o[2] = (short)f2bf(v[2]); o[3] = (short)f2bf(v[3]);
    u16* dst = E + (size_t)s * (64 * 512) + (size_t)(t >> 1) * 512 + m * 8 + (t & 1) * 4;
    *(short4v*)dst = o;
}

// ---------------------------------------------------------------------------
// One LSTM step with weight-stationary registers (round-6 version).
// 8 waves = 8-way k-split. h slots BLOCK-MAJOR: h[kg][m][j]. Producer block
// ub writes h[ub*512 + tid] (1KB contiguous); consumer fragment (kg,row)
// reads 16B at kg*512+row*8.
// ---------------------------------------------------------------------------
template<int NS, bool WRITE_H>
__device__ __forceinline__ void compute_tick(
    float* __restrict__ redf,                 // [8][64][RED_PAD]
    const short8 (&wreg)[NS][2],
    const short8 (&areg)[NS][4],
    u16* __restrict__ ho, u16* __restrict__ Hout,
    float& c, float bF, float bI, float bC, float bO, int ub)
{
    const int tid = threadIdx.x;
    const int kw = tid >> 6, l = tid & 63;
    const int ml = l & 15, q = l >> 4;

    floatx4 acc[4][2];
#pragma unroll
    for (int mt = 0; mt < 4; ++mt)
#pragma unroll
        for (int ch = 0; ch < 2; ++ch)
            acc[mt][ch] = (floatx4){0.f, 0.f, 0.f, 0.f};

#pragma unroll
    for (int ci = 0; ci < NS; ++ci)
#pragma unroll
        for (int mt = 0; mt < 4; ++mt) {
            acc[mt][0] = __builtin_amdgcn_mfma_f32_16x16x32_bf16(
                areg[ci][mt], wreg[ci][0], acc[mt][0], 0, 0, 0);
            acc[mt][1] = __builtin_amdgcn_mfma_f32_16x16x32_bf16(
                areg[ci][mt], wreg[ci][1], acc[mt][1], 0, 0, 0);
        }

    // partial -> red[kw][row][col]; D mapping: row = mt*16+q*4+r, col = ch*16+ml
#pragma unroll
    for (int mt = 0; mt < 4; ++mt)
#pragma unroll
        for (int ch = 0; ch < 2; ++ch)
#pragma unroll
            for (int r = 0; r < 4; ++r)
                redf[((size_t)kw * 64 + mt * 16 + q * 4 + r) * RED_PAD + ch * 16 + ml]
                    = acc[mt][ch][r];
    __syncthreads();

    // block reduction over 8 k-slices + epilogue (order identical to round 6)
    const int m = tid >> 3, u = tid & 7;
    const int nl = u * 4;
    float p0 = 0.f, p1 = 0.f, p2 = 0.f, p3 = 0.f;
#pragma unroll
    for (int k2 = 0; k2 < 8; ++k2) {
        floatx4 rv = *(const floatx4*)&redf[((size_t)k2 * 64 + m) * RED_PAD + nl];
        p0 += rv[0]; p1 += rv[1]; p2 += rv[2]; p3 += rv[3];
    }
    float f = sigm(p0 + bF);
    float i = sigm(p1 + bI);
    float g = tanhf(p2 + bC);
    float o = sigm(p3 + bO);
    float cc = f * c + i * g;
    c = cc;
    u16 hb = f2bf(o * tanhf(cc));
    // block-major: offset ub*512 + m*8 + u == ub*512 + tid (contiguous 1KB)
    __hip_atomic_store(&ho[(size_t)ub * 512 + tid], hb,
                       __ATOMIC_RELAXED, __HIP_MEMORY_SCOPE_AGENT);
    if (WRITE_H)
        __hip_atomic_store(&Hout[(size_t)ub * 512 + tid], hb,
                           __ATOMIC_RELAXED, __HIP_MEMORY_SCOPE_AGENT);
}

// ---------------------------------------------------------------------------
// Persistent kernel. 256 blocks x 512 thr, 73728 B LDS, 1 block/CU.
// Structure = ROUND 6 exactly (764 us measured): two barriers/tick, tid0
// stamp, per-wave line-subset polls, block-major h/E, sc1 write-through.
// THIS ROUND (single change): gated h-fragment loads issued via volatile
// inline-asm global_load_dwordx4 with distinct outputs -> all 24/32 loads
// forced in flight (C++ path capped at ~8 by RA's 128-reg heuristic;
// VGPR=124-128 in rounds 6/7 despite sched_barrier). Explicit
// s_waitcnt vmcnt(0) + sched_barrier(0) before MFMA consumption (rule #18).
// ---------------------------------------------------------------------------
struct PArgs {
    const u16 *E, *Wcat0, *Wcat1;
    u16 *H, *h0c, *h1c;     // h chains: 129 slots of BH, block-major layout
    const float *b_f, *b_i, *b_C, *b_o, *b_f1, *b_i1, *b_C1, *b_o1;
    unsigned* sync;          // flags0 @ +0 (32 lines), flags1 @ +4096 (32 lines)
};

__global__ void __launch_bounds__(512, 2) persist_k(PArgs a) {
    extern __shared__ float redf[];        // [8][64][RED_PAD]

    const int b   = blockIdx.x;
    const int ub  = b & 127;
    const int tid = threadIdx.x;
    const bool L0 = (b < 128);

    const int kw = tid >> 6, l = tid & 63;
    const int ml = l & 15, q = l >> 4;

    // per-thread epilogue state (mapping fixed across ticks)
    const int ug = ub * 8 + (tid & 7);
    const float bF = L0 ? a.b_f[ug] : a.b_f1[ug];
    const float bI = L0 ? a.b_i[ug] : a.b_i1[ug];
    const float bC = L0 ? a.b_C[ug] : a.b_C1[ug];
    const float bO = L0 ? a.b_o[ug] : a.b_o1[ug];
    float c = 0.f;

    unsigned* flags0_u32 = a.sync;                 // 32 lines x 16 u32
    unsigned* flags1_u32 = a.sync + 1024;          // byte offset 4096
    u8* my0 = (u8*)a.sync + (size_t)(ub >> 2) * 64 + (ub & 3);
    u8* my1 = (u8*)a.sync + 4096 + (size_t)(ub >> 2) * 64 + (ub & 3);

    // per-lane byte offset common to all fragment addresses
    const u64 lane_off = (u64)(q * 1024 + ml * 16);

    if (L0) {
        // wave kw owns k-steps S = kw*6 .. kw*6+5 (S<16: E, S>=16: h0)
        short8 wreg[6][2];
#pragma unroll
        for (int ci = 0; ci < 6; ++ci)
#pragma unroll
            for (int ch = 0; ch < 2; ++ch) {
                const int kg = (kw * 6 + ci) * 4 + q;
                wreg[ci][ch] = *(const short8*)(
                    a.Wcat0 + ((size_t)kg * NG + ub * 32 + ch * 16 + ml) * 8);
            }
        // subset gate: flag lines [max(16,kw*6)-16 .. kw*6+5-16]  (<= 6 lines)
        const int Sl   = kw * 6 + 5;
        const bool hasH = (Sl >= 16);
        const int flo  = (kw * 6 > 16) ? (kw * 6 - 16) : 0;
        const int fcnt = hasH ? (Sl - 16 - flo + 1) : 0;

        for (int t = 0; t < 128; ++t) {
            short8 areg[6][4];
            const u16* Et  = a.E   + (size_t)t * (64 * 512);
            const u16* hin = a.h0c + (size_t)t * BH;
            // E-part loads (gate-free; issued before the poll) -- plain C++
#pragma unroll
            for (int ci = 0; ci < 6; ++ci) {
                const int S = kw * 6 + ci;             // wave-uniform
                if (S < 16) {
                    const int kg = S * 4 + q;
#pragma unroll
                    for (int mt = 0; mt < 4; ++mt)
                        areg[ci][mt] = *(const short8*)(
                            Et + (size_t)kg * 512 + (mt * 16 + ml) * 8);
                }
            }
            if (hasH && t > 0) wave_wait_range(flags0_u32, flo, fcnt, (unsigned)t);
            asm volatile("" ::: "memory");
            // h-part loads: forced-MLP asm (wave-uniform branch on kw)
            //   byte off(ci,mt) = (kw*6+ci-16)*4096 + q*1024 + ml*16 + mt*256
            if (kw >= 3) {
                const u64 hb = (u64)(uintptr_t)hin + lane_off;
                u64 ap0 = hb + (u64)(kw * 6 + 1 - 16) * 4096;
                u64 ap1 = ap0 + 8192;
                u64 ap2 = ap1 + 8192;
                LOADPAIR(areg[0], areg[1], ap0);
                LOADPAIR(areg[2], areg[3], ap1);
                LOADPAIR(areg[4], areg[5], ap2);
            } else if (kw == 2) {                      // S=16,17 -> ci 4,5
                const u64 ap = (u64)(uintptr_t)hin + lane_off + 4096;
                LOADPAIR(areg[4], areg[5], ap);
            }
            asm volatile("s_waitcnt vmcnt(0)" ::: "memory");
            __builtin_amdgcn_sched_barrier(0);
            compute_tick<6, true>(redf, wreg, areg,
                                  a.h0c + (size_t)(t + 1) * BH,
                                  a.H + (size_t)t * BH,
                                  c, bF, bI, bC, bO, ub);
            asm volatile("s_waitcnt vmcnt(0)" ::: "memory");   // stores at L3
            __syncthreads();                                   // end-of-tick
            if (tid == 0)
                __hip_atomic_store(my0, (u8)(t + 1),
                                   __ATOMIC_RELAXED, __HIP_MEMORY_SCOPE_AGENT);
        }
    } else {
        // wave kw owns k-steps S = kw*8 .. kw*8+7; kw<4 -> H, kw>=4 -> h1c
        short8 wreg[8][2];
#pragma unroll
        for (int ci = 0; ci < 8; ++ci)
#pragma unroll
            for (int ch = 0; ch < 2; ++ch) {
                const int kg = (kw * 8 + ci) * 4 + q;
                wreg[ci][ch] = *(const short8*)(
                    a.Wcat1 + ((size_t)kg * NG + ub * 32 + ch * 16 + ml) * 8);
            }
        const int kg0 = (kw & 3) * 8;      // k-group base within source
        // subset gate: k-groups [kg0*4, kg0*4+31] -> flag lines [kg0, kg0+7]

        for (int s = 0; s < 128; ++s) {
            short8 areg[8][4];
            const u16* src;
            if (kw >= 4) {
                if (s > 0) wave_wait_range(flags1_u32, kg0, 8, (unsigned)s);
                src = a.h1c + (size_t)s * BH;
            } else {
                wave_wait_range(flags0_u32, kg0, 8, (unsigned)(s + 1));
                src = a.H + (size_t)s * BH;
            }
            asm volatile("" ::: "memory");
            // ALL 32 fragment loads via forced-MLP asm
            //   byte off(ci,mt) = (kg0+ci)*4096 + q*1024 + ml*16 + mt*256
            {
                const u64 sb = (u64)(uintptr_t)src + lane_off + (u64)kg0 * 4096;
                u64 ap0 = sb + 4096;       // pair 0: ci 0,1
                u64 ap1 = sb + 12288;      // pair 1: ci 2,3
                u64 ap2 = sb + 20480;      // pair 2: ci 4,5
                u64 ap3 = sb + 28672;      // pair 3: ci 6,7
                LOADPAIR(areg[0], areg[1], ap0);
                LOADPAIR(areg[2], areg[3], ap1);
                LOADPAIR(areg[4], areg[5], ap2);
                LOADPAIR(areg[6], areg[7], ap3);
            }
            asm volatile("s_waitcnt vmcnt(0)" ::: "memory");
            __builtin_amdgcn_sched_barrier(0);
            compute_tick<8, false>(redf, wreg, areg,
                                   a.h1c + (size_t)(s + 1) * BH, nullptr,
                                   c, bF, bI, bC, bO, ub);
            asm volatile("s_waitcnt vmcnt(0)" ::: "memory");
            __syncthreads();
            if (tid == 0)
                __hip_atomic_store(my1, (u8)(s + 1),
                                   __ATOMIC_RELAXED, __HIP_MEMORY_SCOPE_AGENT);
        }
    }
    // final h1 = h1c + 128*BH (block-major); out_gemm reads that layout
}

// out[64][10000] = h1 @ W_out + b_out   (314 blocks x 32 cols)
// h1 is block-major: element (row m, col k) at h1[(k>>3)*512 + m*8 + (k&7)]
__global__ void __launch_bounds__(256) out_gemm(
    const u16* __restrict__ h1, const u16* __restrict__ W,
    const float* __restrict__ bout, float* __restrict__ out)
{
    __shared__ float red[4][64][33];
    const int tid = threadIdx.x;
    const int w = tid >> 6, l = tid & 63;
    const int ml = l & 15, q = l >> 4;
    const int n0 = blockIdx.x * 32;

    floatx4 acc[4][2];
#pragma unroll
    for (int mi = 0; mi < 4; ++mi)
#pragma unroll
        for (int ni = 0; ni < 2; ++ni)
            acc[mi][ni] = (floatx4){0.f, 0.f, 0.f, 0.f};

#pragma unroll
    for (int ci = 0; ci < 8; ++ci) {
        const int k = (ci * 4 + w) << 5;
        const int kg = (k >> 3) + q;               // k-group of this fragment
        const u16* ar = h1 + (size_t)kg * 512 + ml * 8;
        short8 a0 = *(const short8*)(ar);
        short8 a1 = *(const short8*)(ar + 16 * 8);
        short8 a2 = *(const short8*)(ar + 32 * 8);
        short8 a3 = *(const short8*)(ar + 48 * 8);
        const u16* br = W + ((size_t)((k >> 3) + q) * NOP + n0 + ml) * 8;
        short8 b0 = *(const short8*)(br);
        short8 b1 = *(const short8*)(br + 16 * 8);
        acc[0][0] = __builtin_amdgcn_mfma_f32_16x16x32_bf16(a0, b0, acc[0][0], 0, 0, 0);
        acc[1][0] = __builtin_amdgcn_mfma_f32_16x16x32_bf16(a1, b0, acc[1][0], 0, 0, 0);
        acc[2][0] = __builtin_amdgcn_mfma_f32_16x16x32_bf16(a2, b0, acc[2][0], 0, 0, 0);
        acc[3][0] = __builtin_amdgcn_mfma_f32_16x16x32_bf16(a3, b0, acc[3][0], 0, 0, 0);
        acc[0][1] = __builtin_amdgcn_mfma_f32_16x16x32_bf16(a0, b1, acc[0][1], 0, 0, 0);
        acc[1][1] = __builtin_amdgcn_mfma_f32_16x16x32_bf16(a1, b1, acc[1][1], 0, 0, 0);
        acc[2][1] = __builtin_amdgcn_mfma_f32_16x16x32_bf16(a2, b1, acc[2][1], 0, 0, 0);
        acc[3][1] = __builtin_amdgcn_mfma_f32_16x16x32_bf16(a3, b1, acc[3][1], 0, 0, 0);
    }

#pragma unroll
    for (int mi = 0; mi < 4; ++mi)
#pragma unroll
        for (int ni = 0; ni < 2; ++ni)
#pragma unroll
            for (int r = 0; r < 4; ++r)
                red[w][mi * 16 + q * 4 + r][ni * 16 + ml] = acc[mi][ni][r];
    __syncthreads();

    const int m = tid >> 2;
#pragma unroll
    for (int jj = 0; jj < 8; ++jj) {
        const int nl = (tid & 3) * 8 + jj;
        const int n = n0 + nl;
        if (n < NCLS) {
            float v = red[0][m][nl] + red[1][m][nl] + red[2][m][nl] + red[3][m][nl] + bout[n];
            out[(size_t)m * NCLS + n] = v;
        }
    }
}

// ---------------------------------------------------------------------------
extern "C" void kernel_launch(void* const* d_in, const int* in_sizes, int n_in,
                              void* d_out, int out_size, void* d_ws, size_t ws_size,
                              hipStream_t stream) {
    (void)in_sizes; (void)n_in; (void)out_size; (void)ws_size;
    const int*   X     = (const int*)  d_in[0];
    const float* C     = (const float*)d_in[1];
    const float* W_fx  = (const float*)d_in[2];
    const float* W_fh  = (const float*)d_in[3];
    const float* W_ix  = (const float*)d_in[4];
    const float* W_ih  = (const float*)d_in[5];
    const float* W_Cx  = (const float*)d_in[6];
    const float* W_Ch  = (const float*)d_in[7];
    const float* W_ox  = (const float*)d_in[8];
    const float* W_oh  = (const float*)d_in[9];
    const float* W_fx1 = (const float*)d_in[10];
    const float* W_fh1 = (const float*)d_in[11];
    const float* W_ix1 = (const float*)d_in[12];
    // d_in[13] = W_ih1 — unused: reference reuses W_ih in layer-1 i-gate (bug kept)
    const float* W_Cx1 = (const float*)d_in[14];
    const float* W_Ch1 = (const float*)d_in[15];
    const float* W_ox1 = (const float*)d_in[16];
    const float* W_oh1 = (const float*)d_in[17];
    const float* W_out = (const float*)d_in[18];
    const float* b_f   = (const float*)d_in[19];
    const float* b_i   = (const float*)d_in[20];
    const float* b_C   = (const float*)d_in[21];
    const float* b_o   = (const float*)d_in[22];
    const float* b_f1  = (const float*)d_in[23];
    const float* b_i1  = (const float*)d_in[24];
    const float* b_C1  = (const float*)d_in[25];
    const float* b_o1  = (const float*)d_in[26];
    const float* b_out = (const float*)d_in[27];
    float* out = (float*)d_out;

    // workspace carve (~105 MB)
    uint8_t* ws = (uint8_t*)d_ws;
    const size_t SZ_WCAT0 = (size_t)1536 * NG * 2;      // 12 MB
    const size_t SZ_WCAT1 = (size_t)2048 * NG * 2;      // 16 MB
    const size_t SZ_WOUTP = (size_t)1024 * NOP * 2;     // ~20 MB
    const size_t SZ_E     = (size_t)SEQ * BATCH * EMB * 2;    // 8 MB
    const size_t SZ_H     = (size_t)SEQ * BH * 2;             // 16 MB
    const size_t SZ_HC    = (size_t)(SEQ + 1) * BH * 2;       // 16.6 MB per chain
    u16*   Wcat0 = (u16*)ws;                         ws += SZ_WCAT0;
    u16*   Wcat1 = (u16*)ws;                         ws += SZ_WCAT1;
    u16*   WoutP = (u16*)ws;                         ws += SZ_WOUTP;
    u16*   E     = (u16*)ws;                         ws += SZ_E;
    u16*   H     = (u16*)ws;                         ws += SZ_H;
    u16*   h0c   = (u16*)ws;                         ws += SZ_HC;
    u16*   h1c   = (u16*)ws;                         ws += SZ_HC;
    unsigned* syncw = (unsigned*)ws;                 ws += 8192;

    // allow 73728 B dynamic LDS (host-side, capture-safe)
    hipFuncSetAttribute((const void*)persist_k,
                        hipFuncAttributeMaxDynamicSharedMemorySize, LDS_BYTES);

    // --- pack weights + embed (parallel prep work)
    pack_gates<<<256, 256, 0, stream>>>(W_fx, W_ix, W_Cx, W_ox, Wcat0, 64, 0);
    pack_gates<<<512, 256, 0, stream>>>(W_fh, W_ih, W_Ch, W_oh, Wcat0, 128, 64);
    pack_gates<<<512, 256, 0, stream>>>(W_fx1, W_ix1, W_Cx1, W_ox1, Wcat1, 128, 0);
    pack_gates<<<512, 256, 0, stream>>>(W_fh1, W_ih, W_Ch1, W_oh1, Wcat1, 128, 128);
    hipMemsetAsync(WoutP, 0, SZ_WOUTP, stream);
    pack_wout<<<(128 * NCLS + 255) / 256, 256, 0, stream>>>(W_out, WoutP);
    embed_k<<<SEQ * BATCH, 128, 0, stream>>>(X, C, E);

    // --- zero slot 0 of both h chains + sync flags
    hipMemsetAsync(h0c, 0, (size_t)BH * 2, stream);
    hipMemsetAsync(h1c, 0, (size_t)BH * 2, stream);
    hipMemsetAsync(syncw, 0, 8192, stream);

    // --- the whole recurrence in one launch
    PArgs pa;
    pa.E = E; pa.Wcat0 = Wcat0; pa.Wcat1 = Wcat1;
    pa.H = H; pa.h0c = h0c; pa.h1c = h1c;
    pa.b_f = b_f; pa.b_i = b_i; pa.b_C = b_C; pa.b_o = b_o;
    pa.b_f1 = b_f1; pa.b_i1 = b_i1; pa.b_C1 = b_C1; pa.b_o1 = b_o1;
    pa.sync = syncw;
    persist_k<<<256, 512, LDS_BYTES, stream>>>(pa);

    // --- output projection (kernel boundary = full coherence for h1c final slot)
    out_gemm<<<314, 256, 0, stream>>>(h1c + (size_t)SEQ * BH, WoutP, b_out, out);
}